// Round 1
// baseline (193.875 us; speedup 1.0000x reference)
//
#include <hip/hip_runtime.h>
#include <stdint.h>

#define N_LOC 216320        // 5 * 208 * 208
#define PLANE 43264         // 208 * 208
#define GRIDW 208
#define NCAP 2048           // candidate cap (expected ~1030)
#define TOPK 1024

typedef unsigned long long u64;
typedef uint32_t u32;

// ---- workspace layout (bytes) ----
#define OFF_KEYS      0u          // u32[216320]
#define OFF_HIST      865280u     // u32[4096]
#define OFF_CTR       881664u     // u32[8]  [0]=M, [1]=thr_lo
#define OFF_CAND      881696u     // u64[2048]
#define OFF_SELIDX    898080u     // u32[1024]
#define OFF_CONF      902176u     // f32[1024]
#define OFF_BOX       906272u     // float4[1024] (16B aligned)
#define OFF_CLS       922656u     // f32[1024]
#define OFF_CANDMASK  926752u     // u64[16]
#define OFF_NZ        926880u     // u64[16]
#define OFF_SUP       927008u     // u64[1024*16] = 128 KB
// total ~1.06 MB

__global__ void k_init(u32* hist, u32* ctr, u64* nz) {
    int t = blockIdx.x * 256 + threadIdx.x;
    if (t < 4096) hist[t] = 0;
    if (t < 8) ctr[t] = 0;
    if (t < 16) nz[t] = 0;
}

// conf scores + histogram of mantissa bits [22:11]
__global__ void k_scores(const float* __restrict__ x, u32* keys, u32* hist) {
    int i = blockIdx.x * 256 + threadIdx.x;
    if (i >= N_LOC) return;
    int a = i / PLANE;
    int hw = i - a * PLANE;
    float v = x[(a * 85 + 4) * PLANE + hw];
    float cf = 1.0f / (1.0f + expf(-v));
    u32 key = (cf > 0.5f) ? __float_as_uint(cf) : 0u;
    keys[i] = key;
    if (key) {
        u32 bin = (key >= 0x3F800000u) ? 4095u : ((key >> 11) & 0xFFFu);
        atomicAdd(&hist[bin], 1u);
    }
}

// find bin containing rank TOPK (counting from the top); write threshold key
__global__ void k_findbin(const u32* hist, u32* ctr) {
    __shared__ u32 lhist[4096];
    __shared__ u32 csum[256];
    int t = threadIdx.x; // 256 threads
    u32 s = 0;
    for (int b = 0; b < 16; b++) {
        u32 h = hist[t * 16 + b];
        lhist[t * 16 + b] = h;
        s += h;
    }
    csum[t] = s;
    __syncthreads();
    if (t == 0) {
        u32 acc = 0;
        int selB = 0;
        int c = 255;
        for (; c >= 0; c--) {
            if (acc + csum[c] >= (u32)TOPK) break;
            acc += csum[c];
        }
        if (c >= 0) {
            int b = c * 16 + 15;
            for (; b >= c * 16; b--) {
                acc += lhist[b];
                if (acc >= (u32)TOPK) break;
            }
            if (b < c * 16) b = c * 16;   // defensive; cannot happen
            selB = b;
        }
        ctr[1] = 0x3F000000u | ((u32)selB << 11);
    }
}

// compact candidates with key >= threshold into cand[] as (key<<32)|~idx
__global__ void k_compact(const u32* keys, u32* ctr, u64* cand) {
    int i = blockIdx.x * 256 + threadIdx.x;
    if (i >= N_LOC) return;
    u32 k = keys[i];
    u32 thr = ctr[1];
    if (k >= thr && k != 0u) {
        u32 pos = atomicAdd(&ctr[0], 1u);
        if (pos < (u32)NCAP)
            cand[pos] = ((u64)k << 32) | (u64)(~(u32)i);
    }
}

// bitonic sort 2048 u64 keys descending; emit sorted top-1024 + candmask
__global__ void __launch_bounds__(1024) k_sort(const u32* ctr, const u64* cand,
                                               u32* sel_idx, float* conf, u64* candmask) {
    __shared__ u64 arr[NCAP];
    int t = threadIdx.x;
    u32 M = ctr[0];
    if (M > (u32)NCAP) M = NCAP;
    for (int e = t; e < NCAP; e += 1024) arr[e] = ((u32)e < M) ? cand[e] : 0ull;
    __syncthreads();
    for (int k = 2; k <= NCAP; k <<= 1) {
        for (int j = k >> 1; j > 0; j >>= 1) {
            int p = t;
            int e = ((p & ~(j - 1)) << 1) | (p & (j - 1));
            int l = e | j;
            u64 a = arr[e], b = arr[l];
            bool desc = ((e & k) == 0);
            if (desc ? (a < b) : (a > b)) { arr[e] = b; arr[l] = a; }
            __syncthreads();
        }
    }
    // t in [0,1024) == TOPK, all threads
    u64 v = arr[t];
    u32 key = (u32)(v >> 32);
    bool valid = (key != 0u);
    sel_idx[t] = valid ? ~((u32)v) : 0u;
    conf[t] = valid ? __uint_as_float(key) : 0.0f;
    u64 m = __ballot(valid);
    if ((t & 63) == 0) candmask[t >> 6] = m;
}

// full decode only for selected 1024
__global__ void k_decode(const float* __restrict__ x, const float* __restrict__ anchors,
                         const u32* sel_idx, const float* conf,
                         float4* box, float* clsf) {
    int r = blockIdx.x * 256 + threadIdx.x;
    if (r >= TOPK) return;
    float cf = conf[r];
    if (cf <= 0.0f) {
        box[r] = make_float4(0.f, 0.f, 0.f, 0.f);
        clsf[r] = 0.f;
        return;
    }
    u32 i = sel_idx[r];
    u32 a = i / PLANE;
    u32 hw = i - a * PLANE;
    u32 h = hw / GRIDW;
    u32 w = hw - h * GRIDW;
    const float* base = x + (a * 85u) * PLANE + hw;
    float p0 = base[0];
    float p1 = base[PLANE];
    float p2 = base[2 * PLANE];
    float p3 = base[3 * PLANE];
    float bx = (1.0f / (1.0f + expf(-p0)) + (float)w) * 32.0f;
    float by = (1.0f / (1.0f + expf(-p1)) + (float)h) * 32.0f;
    float bw = (expf(p2) * anchors[a * 2 + 0]) * 32.0f;
    float bh = (expf(p3) * anchors[a * 2 + 1]) * 32.0f;
    float m = base[5 * PLANE];
    int cls = 0;
    for (int c = 1; c < 80; c++) {
        float vv = base[(5 + c) * PLANE];
        if (vv > m) { m = vv; cls = c; }
    }
    box[r] = make_float4(bx, by, bw, bh);
    clsf[r] = (float)cls;
}

// suppression bitmatrix: sup[i][w] bit j=1 iff (j>i, same class, IoU>=0.5)
__global__ void __launch_bounds__(256) k_supmat(const float4* __restrict__ box,
                                                const float* __restrict__ clsf,
                                                u64* sup, u64* nz) {
    int i = blockIdx.x;
    float4 bi = box[i];
    float ci = clsf[i];
    // faithful to reference: (c - s)/2 parenthesization
    float x1min = (bi.x - bi.z) * 0.5f, x1max = (bi.x + bi.z) * 0.5f;
    float y1min = (bi.y - bi.w) * 0.5f, y1max = (bi.y + bi.w) * 0.5f;
    float a1 = fabsf((x1max - x1min) * (y1max - y1min));
    int t = threadIdx.x;
    u64 any = 0;
    __shared__ u64 wany[4];
    for (int c = 0; c < 4; c++) {
        int j = c * 256 + t;
        bool s = false;
        if (j > i) {
            float4 bj = box[j];
            float x2min = (bj.x - bj.z) * 0.5f, x2max = (bj.x + bj.z) * 0.5f;
            float y2min = (bj.y - bj.w) * 0.5f, y2max = (bj.y + bj.w) * 0.5f;
            float iw = fmaxf(fminf(x1max, x2max) - fmaxf(x1min, x2min), 0.0f);
            float ih = fmaxf(fminf(y1max, y2max) - fmaxf(y1min, y2min), 0.0f);
            float inter = iw * ih;
            float a2 = fabsf((x2max - x2min) * (y2max - y2min));
            float iou = inter / (a1 + a2 - inter + 1e-6f);
            s = (iou >= 0.5f) && (clsf[j] == ci);
        }
        u64 msk = __ballot(s);
        if ((t & 63) == 0) sup[i * 16 + c * 4 + (t >> 6)] = msk;
        any |= msk;
    }
    if ((t & 63) == 0) wany[t >> 6] = any;
    __syncthreads();
    if (t == 0) {
        u64 tot = wany[0] | wany[1] | wany[2] | wany[3];
        if (tot) atomicOr(&nz[i >> 6], 1ull << (i & 63));
    }
}

// greedy scan (1 wave, only nonzero rows touched) + write output
__global__ void __launch_bounds__(1024) k_nms_out(const u64* __restrict__ sup,
                                                  const u64* __restrict__ nz,
                                                  const u64* __restrict__ candmask,
                                                  const float4* __restrict__ box,
                                                  const float* __restrict__ conf,
                                                  const float* __restrict__ clsf,
                                                  float* __restrict__ out) {
    __shared__ u64 remLDS[16];
    int t = threadIdx.x;
    if (t < 64) {
        int lane = t;
        u64 rem = 0;
        u64 cnd = (lane < 16) ? candmask[lane] : 0ull;
        u64 nzw = (lane < 16) ? nz[lane] : 0ull;
        for (int g = 0; g < 16; g++) {
            u64 myword = cnd & ~rem;
            u64 live = __shfl(myword, g);
            u64 act = live & __shfl(nzw, g);
            while (act) {
                int b = __builtin_ctzll(act);
                int i = g * 64 + b;
                u64 row = (lane < 16) ? sup[i * 16 + lane] : 0ull;
                rem |= row;
                u64 row_g = __shfl(row, g);
                act &= ~row_g;
                act &= ~(1ull << b);
            }
        }
        if (lane < 16) remLDS[lane] = rem;
    }
    __syncthreads();
    int r = t;
    u64 cw = candmask[r >> 6];
    u64 rw = remLDS[r >> 6];
    bool kept = ((cw >> (r & 63)) & 1ull) && !((rw >> (r & 63)) & 1ull);
    float4 b4 = box[r];
    float cf = conf[r];
    float cl = clsf[r];
    float* o = out + r * 6;
    if (kept) {
        o[0] = b4.x; o[1] = b4.y; o[2] = b4.z; o[3] = b4.w; o[4] = cf; o[5] = cl;
    } else {
        o[0] = 0.f; o[1] = 0.f; o[2] = 0.f; o[3] = 0.f; o[4] = 0.f; o[5] = 0.f;
    }
}

extern "C" void kernel_launch(void* const* d_in, const int* in_sizes, int n_in,
                              void* d_out, int out_size, void* d_ws, size_t ws_size,
                              hipStream_t stream) {
    const float* x = (const float*)d_in[0];
    const float* anchors = (const float*)d_in[1];
    float* out = (float*)d_out;
    char* ws = (char*)d_ws;

    u32* keys     = (u32*)(ws + OFF_KEYS);
    u32* hist     = (u32*)(ws + OFF_HIST);
    u32* ctr      = (u32*)(ws + OFF_CTR);
    u64* cand     = (u64*)(ws + OFF_CAND);
    u32* sel_idx  = (u32*)(ws + OFF_SELIDX);
    float* conf   = (float*)(ws + OFF_CONF);
    float4* box   = (float4*)(ws + OFF_BOX);
    float* clsf   = (float*)(ws + OFF_CLS);
    u64* candmask = (u64*)(ws + OFF_CANDMASK);
    u64* nz       = (u64*)(ws + OFF_NZ);
    u64* sup      = (u64*)(ws + OFF_SUP);

    k_init<<<16, 256, 0, stream>>>(hist, ctr, nz);
    k_scores<<<(N_LOC + 255) / 256, 256, 0, stream>>>(x, keys, hist);
    k_findbin<<<1, 256, 0, stream>>>(hist, ctr);
    k_compact<<<(N_LOC + 255) / 256, 256, 0, stream>>>(keys, ctr, cand);
    k_sort<<<1, 1024, 0, stream>>>(ctr, cand, sel_idx, conf, candmask);
    k_decode<<<4, 256, 0, stream>>>(x, anchors, sel_idx, conf, box, clsf);
    k_supmat<<<TOPK, 256, 0, stream>>>(box, clsf, sup, nz);
    k_nms_out<<<1, 1024, 0, stream>>>(sup, nz, candmask, box, conf, clsf, out);
}

// Round 2
// 138.002 us; speedup vs baseline: 1.4049x; 1.4049x over previous
//
#include <hip/hip_runtime.h>
#include <stdint.h>

#define N_LOC 216320        // 5 * 208 * 208
#define PLANE 43264         // 208 * 208
#define GRIDW 208
#define NCAP 2048           // candidate cap (expected ~1060)
#define TOPK 1024

typedef unsigned long long u64;
typedef uint32_t u32;

// ---- workspace layout (bytes) ----
#define OFF_KEYS      0u          // u32[216320]
#define OFF_HIST      865280u     // u32[4096]
#define OFF_CTR       881664u     // u32[8]  [0]=M, [1]=thr
#define OFF_CAND      881696u     // u64[2048]
#define OFF_SELIDX    898080u     // u32[1024]
#define OFF_CONF      902176u     // f32[1024]
#define OFF_BOX       906272u     // float4[1024] (16B aligned)
#define OFF_CLS       922656u     // f32[1024]
#define OFF_NZ        926752u     // u64[16]
#define OFF_SUP       926880u     // u64[1024*16] = 128 KB
// total ~1.06 MB

__global__ void k_init(u32* hist, u32* ctr, u64* nz, float* conf) {
    int t = blockIdx.x * 256 + threadIdx.x;
    if (t < 4096) hist[t] = 0;
    if (t < 8) ctr[t] = 0;
    if (t < 16) nz[t] = 0;
    if (t < 1024) conf[t] = 0.0f;
}

// conf scores + histogram of mantissa bits [22:11]
__global__ void k_scores(const float* __restrict__ x, u32* keys, u32* hist) {
    int i = blockIdx.x * 256 + threadIdx.x;
    if (i >= N_LOC) return;
    int a = i / PLANE;
    int hw = i - a * PLANE;
    float v = x[(a * 85 + 4) * PLANE + hw];
    float cf = 1.0f / (1.0f + expf(-v));
    u32 key = (cf > 0.5f) ? __float_as_uint(cf) : 0u;
    keys[i] = key;
    if (key) {
        u32 bin = (key >= 0x3F800000u) ? 4095u : ((key >> 11) & 0xFFFu);
        atomicAdd(&hist[bin], 1u);
    }
}

// find bin containing rank TOPK (counting from the top); write threshold key
__global__ void k_findbin(const u32* hist, u32* ctr) {
    __shared__ u32 lhist[4096];
    __shared__ u32 csum[256];
    int t = threadIdx.x; // 256 threads
    u32 s = 0;
    for (int b = 0; b < 16; b++) {
        u32 h = hist[t * 16 + b];
        lhist[t * 16 + b] = h;
        s += h;
    }
    csum[t] = s;
    __syncthreads();
    if (t == 0) {
        u32 acc = 0;
        int selB = 0;
        int c = 255;
        for (; c >= 0; c--) {
            if (acc + csum[c] >= (u32)TOPK) break;
            acc += csum[c];
        }
        if (c >= 0) {
            int b = c * 16 + 15;
            for (; b >= c * 16; b--) {
                acc += lhist[b];
                if (acc >= (u32)TOPK) break;
            }
            if (b < c * 16) b = c * 16;   // defensive; cannot happen
            selB = b;
        }
        ctr[1] = 0x3F000000u | ((u32)selB << 11);
    }
}

// compact candidates with key >= threshold into cand[] as (key<<32)|~idx
__global__ void k_compact(const u32* keys, u32* ctr, u64* cand) {
    int i = blockIdx.x * 256 + threadIdx.x;
    if (i >= N_LOC) return;
    u32 k = keys[i];
    u32 thr = ctr[1];
    if (k >= thr && k != 0u) {
        u32 pos = atomicAdd(&ctr[0], 1u);
        if (pos < (u32)NCAP)
            cand[pos] = ((u64)k << 32) | (u64)(~(u32)i);
    }
}

// rank-selection: rank(i) = #{j : cand[j] > cand[i]}; keys unique
// -> exact jax.lax.top_k permutation (desc conf, ties -> lower idx).
__global__ void __launch_bounds__(256) k_rank(const u32* __restrict__ ctr,
                                              const u64* __restrict__ cand,
                                              u32* sel_idx, float* conf) {
    u32 M = ctr[0];
    if (M > (u32)NCAP) M = NCAP;
    u32 b = blockIdx.x;
    if (b >= M) return;
    u64 key = cand[b];
    int t = threadIdx.x;
    u32 cnt = 0;
    for (u32 j = (u32)t; j < M; j += 256) cnt += (cand[j] > key) ? 1u : 0u;
    for (int off = 32; off; off >>= 1) cnt += __shfl_down(cnt, off);
    __shared__ u32 scnt;
    if (t == 0) scnt = 0;
    __syncthreads();
    if ((t & 63) == 0) atomicAdd(&scnt, cnt);
    __syncthreads();
    if (t == 0) {
        u32 rank = scnt;
        if (rank < (u32)TOPK) {
            sel_idx[rank] = ~((u32)key);
            conf[rank] = __uint_as_float((u32)(key >> 32));
        }
    }
}

// full decode, one WAVE per selected row: all ~86 channel loads issued in
// parallel across lanes, butterfly argmax over 80 classes.
__global__ void __launch_bounds__(256) k_decode(const float* __restrict__ x,
                                                const float* __restrict__ anchors,
                                                const u32* __restrict__ sel_idx,
                                                const float* __restrict__ conf,
                                                float4* box, float* clsf) {
    int wave = (blockIdx.x * 256 + threadIdx.x) >> 6;   // 0..1023
    int lane = threadIdx.x & 63;
    float cf = conf[wave];
    if (cf <= 0.0f) {
        if (lane == 0) { box[wave] = make_float4(0.f, 0.f, 0.f, 0.f); clsf[wave] = 0.f; }
        return;
    }
    u32 i = sel_idx[wave];
    u32 a = i / PLANE;
    u32 hw = i - a * PLANE;
    u32 h = hw / GRIDW;
    u32 w = hw - h * GRIDW;
    const float* base = x + (size_t)(a * 85u) * PLANE + hw;
    // classes: lane l -> class l; lanes 0..15 also class 64+l
    float v0 = base[(5 + lane) * PLANE];
    int   c0 = lane;
    if (lane < 16) {
        float v1 = base[(5 + 64 + lane) * PLANE];
        if (v1 > v0) { v0 = v1; c0 = 64 + lane; }   // tie keeps lower idx
    }
    float pv = (lane < 4) ? base[lane * PLANE] : 0.f;
    // butterfly argmax, tie -> lower class index (jnp.argmax first-occurrence)
    for (int off = 32; off; off >>= 1) {
        float ov = __shfl_xor(v0, off);
        int   oc = __shfl_xor(c0, off);
        if (ov > v0 || (ov == v0 && oc < c0)) { v0 = ov; c0 = oc; }
    }
    float p0 = __shfl(pv, 0);
    float p1 = __shfl(pv, 1);
    float p2 = __shfl(pv, 2);
    float p3 = __shfl(pv, 3);
    if (lane == 0) {
        float bx = (1.0f / (1.0f + expf(-p0)) + (float)w) * 32.0f;
        float by = (1.0f / (1.0f + expf(-p1)) + (float)h) * 32.0f;
        float bw = (expf(p2) * anchors[a * 2 + 0]) * 32.0f;
        float bh = (expf(p3) * anchors[a * 2 + 1]) * 32.0f;
        box[wave] = make_float4(bx, by, bw, bh);
        clsf[wave] = (float)c0;
    }
}

// suppression bitmatrix: sup[i][w] bit j=1 iff (j>i, same class, IoU>=0.5)
__global__ void __launch_bounds__(256) k_supmat(const float4* __restrict__ box,
                                                const float* __restrict__ clsf,
                                                u64* sup, u64* nz) {
    int i = blockIdx.x;
    float4 bi = box[i];
    float ci = clsf[i];
    // faithful to reference: (c - s)/2 parenthesization
    float x1min = (bi.x - bi.z) * 0.5f, x1max = (bi.x + bi.z) * 0.5f;
    float y1min = (bi.y - bi.w) * 0.5f, y1max = (bi.y + bi.w) * 0.5f;
    float a1 = fabsf((x1max - x1min) * (y1max - y1min));
    int t = threadIdx.x;
    u64 any = 0;
    __shared__ u64 wany[4];
    for (int c = 0; c < 4; c++) {
        int j = c * 256 + t;
        bool s = false;
        if (j > i) {
            float4 bj = box[j];
            float x2min = (bj.x - bj.z) * 0.5f, x2max = (bj.x + bj.z) * 0.5f;
            float y2min = (bj.y - bj.w) * 0.5f, y2max = (bj.y + bj.w) * 0.5f;
            float iw = fmaxf(fminf(x1max, x2max) - fmaxf(x1min, x2min), 0.0f);
            float ih = fmaxf(fminf(y1max, y2max) - fmaxf(y1min, y2min), 0.0f);
            float inter = iw * ih;
            float a2 = fabsf((x2max - x2min) * (y2max - y2min));
            float iou = inter / (a1 + a2 - inter + 1e-6f);
            s = (iou >= 0.5f) && (clsf[j] == ci);
        }
        u64 msk = __ballot(s);
        if ((t & 63) == 0) sup[i * 16 + c * 4 + (t >> 6)] = msk;
        any |= msk;
    }
    if ((t & 63) == 0) wany[t >> 6] = any;
    __syncthreads();
    if (t == 0) {
        u64 tot = wany[0] | wany[1] | wany[2] | wany[3];
        if (tot) atomicOr(&nz[i >> 6], 1ull << (i & 63));
    }
}

// greedy scan (1 wave, only nonzero rows touched) + write output
__global__ void __launch_bounds__(1024) k_nms_out(const u64* __restrict__ sup,
                                                  const u64* __restrict__ nz,
                                                  const float4* __restrict__ box,
                                                  const float* __restrict__ conf,
                                                  const float* __restrict__ clsf,
                                                  float* __restrict__ out) {
    __shared__ u64 candLDS[16];
    __shared__ u64 remLDS[16];
    int t = threadIdx.x;
    float cf = conf[t];
    bool valid = cf > 0.0f;
    u64 bm = __ballot(valid);
    if ((t & 63) == 0) candLDS[t >> 6] = bm;
    __syncthreads();
    if (t < 64) {
        int lane = t;
        u64 rem = 0;
        u64 cnd = (lane < 16) ? candLDS[lane] : 0ull;
        u64 nzw = (lane < 16) ? nz[lane] : 0ull;
        for (int g = 0; g < 16; g++) {
            u64 myword = cnd & ~rem;
            u64 live = __shfl(myword, g);
            u64 act = live & __shfl(nzw, g);
            while (act) {
                int b = __builtin_ctzll(act);
                int i = g * 64 + b;
                u64 row = (lane < 16) ? sup[i * 16 + lane] : 0ull;
                rem |= row;
                u64 row_g = __shfl(row, g);
                act &= ~row_g;
                act &= ~(1ull << b);
            }
        }
        if (lane < 16) remLDS[lane] = rem;
    }
    __syncthreads();
    int r = t;
    u64 rw = remLDS[r >> 6];
    bool kept = valid && !((rw >> (r & 63)) & 1ull);
    float4 b4 = box[r];
    float cl = clsf[r];
    float* o = out + r * 6;
    if (kept) {
        o[0] = b4.x; o[1] = b4.y; o[2] = b4.z; o[3] = b4.w; o[4] = cf; o[5] = cl;
    } else {
        o[0] = 0.f; o[1] = 0.f; o[2] = 0.f; o[3] = 0.f; o[4] = 0.f; o[5] = 0.f;
    }
}

extern "C" void kernel_launch(void* const* d_in, const int* in_sizes, int n_in,
                              void* d_out, int out_size, void* d_ws, size_t ws_size,
                              hipStream_t stream) {
    const float* x = (const float*)d_in[0];
    const float* anchors = (const float*)d_in[1];
    float* out = (float*)d_out;
    char* ws = (char*)d_ws;

    u32* keys     = (u32*)(ws + OFF_KEYS);
    u32* hist     = (u32*)(ws + OFF_HIST);
    u32* ctr      = (u32*)(ws + OFF_CTR);
    u64* cand     = (u64*)(ws + OFF_CAND);
    u32* sel_idx  = (u32*)(ws + OFF_SELIDX);
    float* conf   = (float*)(ws + OFF_CONF);
    float4* box   = (float4*)(ws + OFF_BOX);
    float* clsf   = (float*)(ws + OFF_CLS);
    u64* nz       = (u64*)(ws + OFF_NZ);
    u64* sup      = (u64*)(ws + OFF_SUP);

    k_init<<<16, 256, 0, stream>>>(hist, ctr, nz, conf);
    k_scores<<<(N_LOC + 255) / 256, 256, 0, stream>>>(x, keys, hist);
    k_findbin<<<1, 256, 0, stream>>>(hist, ctr);
    k_compact<<<(N_LOC + 255) / 256, 256, 0, stream>>>(keys, ctr, cand);
    k_rank<<<NCAP, 256, 0, stream>>>(ctr, cand, sel_idx, conf);
    k_decode<<<256, 256, 0, stream>>>(x, anchors, sel_idx, conf, box, clsf);
    k_supmat<<<TOPK, 256, 0, stream>>>(box, clsf, sup, nz);
    k_nms_out<<<1, 1024, 0, stream>>>(sup, nz, box, conf, clsf, out);
}